// Round 1
// baseline (221.223 us; speedup 1.0000x reference)
//
#include <hip/hip_runtime.h>
#include <hip/hip_bf16.h>

// Problem constants (from reference setup_inputs)
#define Bc 2
#define Cc 64
#define Hc 128
#define Wc 128
#define Oc 64
#define Kc 9          // 3x3
#define NOFF 27       // DG*3*K

// ---------------------------------------------------------------------------
// Kernel 1: transpose weight (O,C,3,3) -> Wt[ck][o], ck = c*9+k
// ---------------------------------------------------------------------------
__global__ void transpose_w_kernel(const float* __restrict__ w, float* __restrict__ wt) {
    int t = blockIdx.x * 256 + threadIdx.x;
    if (t < 576 * 64) {
        int ck = t >> 6;
        int o  = t & 63;
        wt[t] = w[o * 576 + ck];
    }
}

// ---------------------------------------------------------------------------
// Kernel 2: offset conv: off[b][oc][h][w] = sum_{c,kh,kw} x * offset_w + ob
// block = 256 threads: 64 pixels (tx) x 4 channel-quarters (qg, 16 ch each)
// grid = B*H*2 = 512
// ---------------------------------------------------------------------------
__global__ __launch_bounds__(256) void offsets_conv_kernel(
    const float* __restrict__ x, const float* __restrict__ ow,
    const float* __restrict__ ob, float* __restrict__ off) {
    int bid = blockIdx.x;
    int b   = bid >> 8;          // H*2 = 256 blocks per batch
    int rem = bid & 255;
    int h   = rem >> 1;
    int w0  = (rem & 1) << 6;
    int tid = threadIdx.x;
    int qg  = tid >> 6;          // channel quarter 0..3
    int px  = tid & 63;          // pixel within row-half
    int wx  = w0 + px;

    float acc[NOFF];
#pragma unroll
    for (int oc = 0; oc < NOFF; ++oc) acc[oc] = 0.f;

    for (int c = qg * 16; c < qg * 16 + 16; ++c) {
        const float* xp = x + (size_t)(b * Cc + c) * Hc * Wc;
        float xv[9];
#pragma unroll
        for (int i = 0; i < 3; ++i) {
            int y = h - 1 + i;
            bool vy = (y >= 0) & (y < Hc);
#pragma unroll
            for (int j = 0; j < 3; ++j) {
                int xx = wx - 1 + j;
                bool v = vy & (xx >= 0) & (xx < Wc);
                xv[i * 3 + j] = v ? xp[y * Wc + xx] : 0.f;
            }
        }
#pragma unroll
        for (int oc = 0; oc < NOFF; ++oc) {
            const float* wq = ow + oc * 576 + c * 9;  // uniform -> scalar loads
            float s = xv[0] * wq[0] + xv[1] * wq[1] + xv[2] * wq[2]
                    + xv[3] * wq[3] + xv[4] * wq[4] + xv[5] * wq[5]
                    + xv[6] * wq[6] + xv[7] * wq[7] + xv[8] * wq[8];
            acc[oc] += s;
        }
    }

    __shared__ float red[4 * NOFF * 64];   // 27.6 KB
#pragma unroll
    for (int oc = 0; oc < NOFF; ++oc)
        red[(qg * NOFF + oc) * 64 + px] = acc[oc];
    __syncthreads();

    for (int t = tid; t < NOFF * 64; t += 256) {
        int oc = t >> 6, p = t & 63;
        float s = red[(0 * NOFF + oc) * 64 + p] + red[(1 * NOFF + oc) * 64 + p]
                + red[(2 * NOFF + oc) * 64 + p] + red[(3 * NOFF + oc) * 64 + p]
                + ob[oc];
        off[((size_t)(b * NOFF + oc) * Hc + h) * Wc + w0 + p] = s;
    }
}

// ---------------------------------------------------------------------------
// Kernel 3: main deformable conv.
// block = 256 threads handles (b, h, 64 w-pixels). grid = B*H*2 = 512.
// Phase 0: build bilinear table per (k,p): 4 weights (mask+validity folded),
//          clipped row offsets / cols.
// Phase 1: 4 chunks of 16 channels: sample 144x64 tile into LDS, then
//          64(o) x 64(p) matvec with 4x4 register tile per thread.
// ---------------------------------------------------------------------------
__global__ __launch_bounds__(256) void deform_main_kernel(
    const float* __restrict__ x, const float* __restrict__ Wt,
    const float* __restrict__ bias, const float* __restrict__ off,
    float* __restrict__ out) {
    int bid = blockIdx.x;
    int b   = bid >> 8;
    int rem = bid & 255;
    int h   = rem >> 1;
    int w0  = (rem & 1) << 6;
    int tid = threadIdx.x;

    __shared__ float4 wgt[576];       // [k*64+p] corner weights (mask folded)
    __shared__ int4   sidx[576];      // {cy0*W, cy1*W, cx0, cx1}
    __shared__ float  S[144 * 64];    // sample tile [ckl][p]   36 KB
    __shared__ float  tmp[NOFF * 64]; // raw offsets [ch][p]    6.9 KB

    const float* offb = off + (size_t)b * NOFF * Hc * Wc + h * Wc + w0;
    for (int t = tid; t < NOFF * 64; t += 256) {
        int ch = t >> 6, p = t & 63;
        tmp[t] = offb[(size_t)ch * Hc * Wc + p];
    }
    __syncthreads();

    for (int t = tid; t < 576; t += 256) {
        int k = t >> 6, p = t & 63;
        float dy = tmp[k * 64 + p];
        float dx = tmp[(9 + k) * 64 + p];
        float mm = tmp[(18 + k) * 64 + p];
        float m  = 1.f / (1.f + __expf(-mm));   // sigmoid
        float py = (float)(h - 1 + k / 3) + dy;
        float px = (float)(w0 + p - 1 + k % 3) + dx;
        float y0f = floorf(py), x0f = floorf(px);
        float fy = py - y0f, fx = px - x0f;
        int y0 = (int)y0f, x0i = (int)x0f;
        float vy0 = (y0 >= 0 && y0 < Hc) ? 1.f : 0.f;
        float vy1 = (y0 + 1 >= 0 && y0 + 1 < Hc) ? 1.f : 0.f;
        float vx0 = (x0i >= 0 && x0i < Wc) ? 1.f : 0.f;
        float vx1 = (x0i + 1 >= 0 && x0i + 1 < Wc) ? 1.f : 0.f;
        float w00 = (1.f - fy) * (1.f - fx) * m * vy0 * vx0;
        float w01 = (1.f - fy) * fx         * m * vy0 * vx1;
        float w10 = fy         * (1.f - fx) * m * vy1 * vx0;
        float w11 = fy         * fx         * m * vy1 * vx1;
        int cy0 = min(max(y0, 0), Hc - 1) * Wc;
        int cy1 = min(max(y0 + 1, 0), Hc - 1) * Wc;
        int cx0 = min(max(x0i, 0), Wc - 1);
        int cx1 = min(max(x0i + 1, 0), Wc - 1);
        wgt[t]  = make_float4(w00, w01, w10, w11);
        sidx[t] = make_int4(cy0, cy1, cx0, cx1);
    }
    __syncthreads();

    float acc[4][4];
#pragma unroll
    for (int i = 0; i < 4; ++i)
#pragma unroll
        for (int j = 0; j < 4; ++j) acc[i][j] = 0.f;

    int ty = tid >> 4;   // o-group: o = ty*4 + i
    int tx = tid & 15;   // p-group: p = tx*4 + j

    for (int cc = 0; cc < 4; ++cc) {
        // ---- sample phase: 16 ch x 9 taps x 64 px = 9216 samples ----
        const float* xb = x + (size_t)(b * Cc + cc * 16) * Hc * Wc;
        for (int s = tid; s < 16 * 576; s += 256) {
            int cl = s / 576;
            int kp = s - cl * 576;        // k*64+p, p = lane-consecutive
            float4 w4 = wgt[kp];
            int4  id  = sidx[kp];
            const float* xp = xb + (size_t)cl * Hc * Wc;
            float v00 = xp[id.x + id.z];
            float v01 = xp[id.x + id.w];
            float v10 = xp[id.y + id.z];
            float v11 = xp[id.y + id.w];
            S[s] = w4.x * v00 + w4.y * v01 + w4.z * v10 + w4.w * v11;
        }
        __syncthreads();
        // ---- matvec: acc[o][p] += Wt[ck][o] * S[ckl][p] ----
        const float* wtp = Wt + (size_t)(cc * 144) * 64 + ty * 4;
#pragma unroll 4
        for (int ckl = 0; ckl < 144; ++ckl) {
            float4 wv = *(const float4*)(wtp + ckl * 64);
            float4 sv = *(const float4*)(&S[ckl * 64 + tx * 4]);
            acc[0][0] += wv.x * sv.x; acc[0][1] += wv.x * sv.y;
            acc[0][2] += wv.x * sv.z; acc[0][3] += wv.x * sv.w;
            acc[1][0] += wv.y * sv.x; acc[1][1] += wv.y * sv.y;
            acc[1][2] += wv.y * sv.z; acc[1][3] += wv.y * sv.w;
            acc[2][0] += wv.z * sv.x; acc[2][1] += wv.z * sv.y;
            acc[2][2] += wv.z * sv.z; acc[2][3] += wv.z * sv.w;
            acc[3][0] += wv.w * sv.x; acc[3][1] += wv.w * sv.y;
            acc[3][2] += wv.w * sv.z; acc[3][3] += wv.w * sv.w;
        }
        __syncthreads();
    }

    // epilogue: out[b][o][h][w0 + tx*4 + j] = acc + bias
    float4 b4 = *(const float4*)(bias + ty * 4);
    float bia[4] = {b4.x, b4.y, b4.z, b4.w};
    float* ob = out + ((size_t)(b * Oc) * Hc + h) * Wc + w0 + tx * 4;
#pragma unroll
    for (int i = 0; i < 4; ++i) {
        int o = ty * 4 + i;
        float4 v = make_float4(acc[i][0] + bia[i], acc[i][1] + bia[i],
                               acc[i][2] + bia[i], acc[i][3] + bia[i]);
        *(float4*)(ob + (size_t)o * Hc * Wc) = v;
    }
}

// ---------------------------------------------------------------------------
extern "C" void kernel_launch(void* const* d_in, const int* in_sizes, int n_in,
                              void* d_out, int out_size, void* d_ws, size_t ws_size,
                              hipStream_t stream) {
    const float* x        = (const float*)d_in[0];
    const float* weight   = (const float*)d_in[1];
    const float* bias     = (const float*)d_in[2];
    const float* offset_w = (const float*)d_in[3];
    const float* offset_b = (const float*)d_in[4];
    float* out = (float*)d_out;

    // workspace layout
    float* off = (float*)d_ws;                                   // B*27*H*W floats = 3.4 MB
    float* Wt  = (float*)((char*)d_ws + (size_t)Bc * NOFF * Hc * Wc * sizeof(float)); // 147 KB

    transpose_w_kernel<<<144, 256, 0, stream>>>(weight, Wt);
    offsets_conv_kernel<<<Bc * Hc * 2, 256, 0, stream>>>(x, offset_w, offset_b, off);
    deform_main_kernel<<<Bc * Hc * 2, 256, 0, stream>>>(x, Wt, bias, off, out);
}

// Round 3
// 135.892 us; speedup vs baseline: 1.6279x; 1.6279x over previous
//
#include <hip/hip_runtime.h>
#include <hip/hip_bf16.h>

typedef __attribute__((ext_vector_type(8))) short bf16x8;
typedef __attribute__((ext_vector_type(4))) short bf16x4;
typedef __attribute__((ext_vector_type(4))) float f32x4;

#define Bc 2
#define Cc 64
#define Hc 128
#define Wc 128
#define Oc 64
#define NOFF 27
#define HWc (Hc * Wc)   // 16384

__device__ __forceinline__ short f2bf(float f) {
    __hip_bfloat16 h = __float2bfloat16(f);
    return __builtin_bit_cast(short, h);
}
__device__ __forceinline__ float bf2f(short s) {
    __hip_bfloat16 h = __builtin_bit_cast(__hip_bfloat16, s);
    return __bfloat162float(h);
}

// ---------------------------------------------------------------------------
// Kernel P1: transpose x NCHW -> NHWC fp32.
// grid = B*H*2 = 512 blocks; each block does (b, h, 64-pixel half-row).
// (Round-2 bug: grid was B*H with each block covering only w<64.)
// ---------------------------------------------------------------------------
__global__ __launch_bounds__(256) void transpose_x_kernel(const float* __restrict__ x,
                                                          float* __restrict__ xT) {
    int bid = blockIdx.x;
    int b = bid >> 8, rem = bid & 255;
    int h = rem >> 1, w0 = (rem & 1) << 6;
    __shared__ float tile[64][68];
    int t = threadIdx.x;
    {
        int c = t >> 2, sub = t & 3;
        const float* src = x + ((size_t)(b * Cc + c) * Hc + h) * Wc + w0 + sub * 16;
#pragma unroll
        for (int j = 0; j < 4; ++j) {
            float4 v = *(const float4*)(src + 4 * j);
            *(float4*)&tile[c][sub * 16 + 4 * j] = v;
        }
    }
    __syncthreads();
    {
        int w = t >> 2, cs = (t & 3) << 4;
        float* dst = xT + (((size_t)(b * Hc + h)) * Wc + w0 + w) * Cc + cs;
#pragma unroll
        for (int j = 0; j < 4; ++j) {
            float4 v = make_float4(tile[cs + 4 * j + 0][w], tile[cs + 4 * j + 1][w],
                                   tile[cs + 4 * j + 2][w], tile[cs + 4 * j + 3][w]);
            *(float4*)(dst + 4 * j) = v;
        }
    }
}

// ---------------------------------------------------------------------------
// Kernel P2: pack weights into MFMA A-fragment layout, split bf16 hi/lo.
// A[m][k], m = o, k = kk*64 + c (kk outer taps, c inner channels).
// Frag layout (16x16x32): lane L holds A[L&15][(L>>4)*8 + j], j=0..7.
// Element index: ((mt*18 + ks_g)*64 + lane)*8 + j.
// Main: 4 m-tiles (O=64). Offsets: 2 m-tiles (27 padded to 32).
// ---------------------------------------------------------------------------
__global__ void pack_weights_kernel(const float* __restrict__ w, const float* __restrict__ ow,
                                    short* __restrict__ Ahi, short* __restrict__ Alo,
                                    short* __restrict__ Ohi, short* __restrict__ Olo) {
    int idx = blockIdx.x * 256 + threadIdx.x;
    const int NM = 4 * 18 * 64 * 8;   // 36864
    const int NO = 2 * 18 * 64 * 8;   // 18432
    if (idx < NM) {
        int j = idx & 7, lane = (idx >> 3) & 63, ks = (idx >> 9) % 18, mt = idx / 9216;
        int o  = mt * 16 + (lane & 15);
        int kk = ks >> 1;
        int c  = (ks & 1) * 32 + (lane >> 4) * 8 + j;
        float v = w[(o * Cc + c) * 9 + kk];
        short hi = f2bf(v);
        short lo = f2bf(v - bf2f(hi));
        Ahi[idx] = hi; Alo[idx] = lo;
    } else if (idx < NM + NO) {
        int t2 = idx - NM;
        int j = t2 & 7, lane = (t2 >> 3) & 63, ks = (t2 >> 9) % 18, mt = t2 / 9216;
        int o  = mt * 16 + (lane & 15);
        int kk = ks >> 1;
        int c  = (ks & 1) * 32 + (lane >> 4) * 8 + j;
        float v = (o < NOFF) ? ow[(o * Cc + c) * 9 + kk] : 0.f;
        short hi = f2bf(v);
        short lo = f2bf(v - bf2f(hi));
        Ohi[t2] = hi; Olo[t2] = lo;
    }
}

// ---------------------------------------------------------------------------
// Kernel O: offsets conv as MFMA GEMM.  M=32(27), N=64 px, K=576.
// Per kk tap: build bf16 im2col B-tile in LDS (B-frag layout), 2 k_steps.
// block = 256 (4 waves: wave = n_tile of 16 px). grid = B*H*2 = 512.
// ---------------------------------------------------------------------------
__global__ __launch_bounds__(256) void offsets_mfma_kernel(
    const float* __restrict__ xT, const short* __restrict__ Ohi, const short* __restrict__ Olo,
    const float* __restrict__ obias, float* __restrict__ off) {
    int bid = blockIdx.x;
    int b = bid >> 8, rem = bid & 255;
    int h = rem >> 1, w0 = (rem & 1) << 6;
    int tid = threadIdx.x;
    int lane = tid & 63, wv = tid >> 6;
    int sub = tid & 15, pgg = tid >> 4;       // 16 lanes cover one pixel's channels

    __shared__ __align__(16) short Bl[4096]; // [nt*2+ks][lane][8] bf16 = 8KB

    f32x4 acc0 = {0.f, 0.f, 0.f, 0.f}, acc1 = {0.f, 0.f, 0.f, 0.f};

    const float* xb = xT + (size_t)b * HWc * Cc;
    int ksw = sub >> 3, qw = (sub >> 1) & 3, jw = (sub & 1) * 4;

    for (int kk = 0; kk < 9; ++kk) {
        int di = kk / 3 - 1, dj = kk % 3 - 1;
        int y = h + di;
        bool vy = (y >= 0) && (y < Hc);
        int yc = min(max(y, 0), Hc - 1);
        bf16x4 sv[4];
#pragma unroll
        for (int i = 0; i < 4; ++i) {
            int p = pgg + 16 * i;
            int xw = w0 + p + dj;
            bool v = vy && (xw >= 0) && (xw < Wc);
            int xc = min(max(xw, 0), Wc - 1);
            float4 vv = *(const float4*)(xb + ((size_t)yc * Wc + xc) * Cc + sub * 4);
            float m = v ? 1.f : 0.f;
            sv[i][0] = f2bf(vv.x * m);
            sv[i][1] = f2bf(vv.y * m);
            sv[i][2] = f2bf(vv.z * m);
            sv[i][3] = f2bf(vv.w * m);
        }
        __syncthreads();   // prev iter's B reads done before overwrite
#pragma unroll
        for (int i = 0; i < 4; ++i) {
            int slot8 = (i * 2 + ksw) * 64 + qw * 16 + pgg;
            *(bf16x4*)(&Bl[slot8 * 8 + jw]) = sv[i];
        }
        __syncthreads();
#pragma unroll
        for (int ks = 0; ks < 2; ++ks) {
            bf16x8 bf = *(const bf16x8*)(&Bl[((wv * 2 + ks) * 64 + lane) * 8]);
            int ksg = kk * 2 + ks;
            {
                bf16x8 ah = *(const bf16x8*)(Ohi + ((0 * 18 + ksg) * 64 + lane) * 8);
                bf16x8 al = *(const bf16x8*)(Olo + ((0 * 18 + ksg) * 64 + lane) * 8);
                acc0 = __builtin_amdgcn_mfma_f32_16x16x32_bf16(ah, bf, acc0, 0, 0, 0);
                acc0 = __builtin_amdgcn_mfma_f32_16x16x32_bf16(al, bf, acc0, 0, 0, 0);
            }
            {
                bf16x8 ah = *(const bf16x8*)(Ohi + ((1 * 18 + ksg) * 64 + lane) * 8);
                bf16x8 al = *(const bf16x8*)(Olo + ((1 * 18 + ksg) * 64 + lane) * 8);
                acc1 = __builtin_amdgcn_mfma_f32_16x16x32_bf16(ah, bf, acc1, 0, 0, 0);
                acc1 = __builtin_amdgcn_mfma_f32_16x16x32_bf16(al, bf, acc1, 0, 0, 0);
            }
        }
    }
    // D layout: n = lane&15, m = (lane>>4)*4 + r
    int pl = wv * 16 + (lane & 15);
    int mrow = (lane >> 4) * 4;
    float* op = off + (((size_t)b * NOFF) * Hc + h) * Wc + w0 + pl;
#pragma unroll
    for (int r = 0; r < 4; ++r) {
        int oc = mrow + r;
        if (oc < NOFF) op[(size_t)oc * HWc] = acc0[r] + obias[oc];
        int oc2 = 16 + mrow + r;
        if (oc2 < NOFF) op[(size_t)oc2 * HWc] = acc1[r] + obias[oc2];
    }
}

// ---------------------------------------------------------------------------
// Kernel M: main deformable conv as MFMA GEMM.  M=64, N=64 px, K=576.
// Bilinear table once; per kk tap: coalesced NHWC corner gathers -> bf16
// B-tile in LDS -> 2 k_steps x 4 m_tiles x (hi+lo) MFMA.
// ---------------------------------------------------------------------------
__global__ __launch_bounds__(256) void deform_main_kernel(
    const float* __restrict__ xT, const short* __restrict__ Ahi, const short* __restrict__ Alo,
    const float* __restrict__ bias, const float* __restrict__ off, float* __restrict__ out) {
    int bid = blockIdx.x;
    int b = bid >> 8, rem = bid & 255;
    int h = rem >> 1, w0 = (rem & 1) << 6;
    int tid = threadIdx.x;
    int lane = tid & 63, wv = tid >> 6;
    int sub = tid & 15, pgg = tid >> 4;

    __shared__ float4 wgt[576];
    __shared__ int4   sidx[576];
    __shared__ __align__(16) short Bl[4096];
    __shared__ float  tmp[NOFF * 64];

    const float* offb = off + (size_t)b * NOFF * HWc + h * Wc + w0;
    for (int t = tid; t < NOFF * 64; t += 256)
        tmp[t] = offb[(size_t)(t >> 6) * HWc + (t & 63)];
    __syncthreads();

    for (int t = tid; t < 576; t += 256) {
        int k = t >> 6, p = t & 63;
        float dy = tmp[k * 64 + p];
        float dx = tmp[(9 + k) * 64 + p];
        float mm = tmp[(18 + k) * 64 + p];
        float m  = 1.f / (1.f + __expf(-mm));
        float py = (float)(h - 1 + k / 3) + dy;
        float px = (float)(w0 + p - 1 + k % 3) + dx;
        float y0f = floorf(py), x0f = floorf(px);
        float fy = py - y0f, fx = px - x0f;
        int y0 = (int)y0f, x0i = (int)x0f;
        float vy0 = (y0 >= 0 && y0 < Hc) ? 1.f : 0.f;
        float vy1 = (y0 + 1 >= 0 && y0 + 1 < Hc) ? 1.f : 0.f;
        float vx0 = (x0i >= 0 && x0i < Wc) ? 1.f : 0.f;
        float vx1 = (x0i + 1 >= 0 && x0i + 1 < Wc) ? 1.f : 0.f;
        wgt[t] = make_float4((1.f - fy) * (1.f - fx) * m * vy0 * vx0,
                             (1.f - fy) * fx         * m * vy0 * vx1,
                             fy         * (1.f - fx) * m * vy1 * vx0,
                             fy         * fx         * m * vy1 * vx1);
        int cy0 = min(max(y0, 0), Hc - 1) * Wc;
        int cy1 = min(max(y0 + 1, 0), Hc - 1) * Wc;
        int cx0 = min(max(x0i, 0), Wc - 1);
        int cx1 = min(max(x0i + 1, 0), Wc - 1);
        sidx[t] = make_int4(cy0 + cx0, cy0 + cx1, cy1 + cx0, cy1 + cx1);
    }
    __syncthreads();

    f32x4 acc[4] = {{0.f, 0.f, 0.f, 0.f}, {0.f, 0.f, 0.f, 0.f},
                    {0.f, 0.f, 0.f, 0.f}, {0.f, 0.f, 0.f, 0.f}};

    const float* xb = xT + (size_t)b * HWc * Cc;
    int ksw = sub >> 3, qw = (sub >> 1) & 3, jw = (sub & 1) * 4;

    for (int kk = 0; kk < 9; ++kk) {
        bf16x4 sv[4];
#pragma unroll
        for (int i = 0; i < 4; ++i) {
            int p = pgg + 16 * i;
            float4 w4 = wgt[kk * 64 + p];
            int4  id  = sidx[kk * 64 + p];
            float4 v00 = *(const float4*)(xb + (size_t)id.x * Cc + sub * 4);
            float4 v01 = *(const float4*)(xb + (size_t)id.y * Cc + sub * 4);
            float4 v10 = *(const float4*)(xb + (size_t)id.z * Cc + sub * 4);
            float4 v11 = *(const float4*)(xb + (size_t)id.w * Cc + sub * 4);
            float sx = w4.x * v00.x + w4.y * v01.x + w4.z * v10.x + w4.w * v11.x;
            float sy = w4.x * v00.y + w4.y * v01.y + w4.z * v10.y + w4.w * v11.y;
            float sz = w4.x * v00.z + w4.y * v01.z + w4.z * v10.z + w4.w * v11.z;
            float sw = w4.x * v00.w + w4.y * v01.w + w4.z * v10.w + w4.w * v11.w;
            sv[i][0] = f2bf(sx); sv[i][1] = f2bf(sy);
            sv[i][2] = f2bf(sz); sv[i][3] = f2bf(sw);
        }
        __syncthreads();
#pragma unroll
        for (int i = 0; i < 4; ++i) {
            int slot8 = (i * 2 + ksw) * 64 + qw * 16 + pgg;
            *(bf16x4*)(&Bl[slot8 * 8 + jw]) = sv[i];
        }
        __syncthreads();
#pragma unroll
        for (int ks = 0; ks < 2; ++ks) {
            bf16x8 bf = *(const bf16x8*)(&Bl[((wv * 2 + ks) * 64 + lane) * 8]);
            int ksg = kk * 2 + ks;
#pragma unroll
            for (int mt = 0; mt < 4; ++mt) {
                bf16x8 ah = *(const bf16x8*)(Ahi + ((mt * 18 + ksg) * 64 + lane) * 8);
                bf16x8 al = *(const bf16x8*)(Alo + ((mt * 18 + ksg) * 64 + lane) * 8);
                acc[mt] = __builtin_amdgcn_mfma_f32_16x16x32_bf16(ah, bf, acc[mt], 0, 0, 0);
                acc[mt] = __builtin_amdgcn_mfma_f32_16x16x32_bf16(al, bf, acc[mt], 0, 0, 0);
            }
        }
    }

    int pl = wv * 16 + (lane & 15);
    int mrow = (lane >> 4) * 4;
    float* ob = out + ((size_t)b * Oc * Hc + h) * Wc + w0 + pl;
#pragma unroll
    for (int mt = 0; mt < 4; ++mt)
#pragma unroll
        for (int r = 0; r < 4; ++r) {
            int o = mt * 16 + mrow + r;
            ob[(size_t)o * HWc] = acc[mt][r] + bias[o];
        }
}

// ---------------------------------------------------------------------------
extern "C" void kernel_launch(void* const* d_in, const int* in_sizes, int n_in,
                              void* d_out, int out_size, void* d_ws, size_t ws_size,
                              hipStream_t stream) {
    const float* x        = (const float*)d_in[0];
    const float* weight   = (const float*)d_in[1];
    const float* bias     = (const float*)d_in[2];
    const float* offset_w = (const float*)d_in[3];
    const float* offset_b = (const float*)d_in[4];
    float* out = (float*)d_out;

    char* ws = (char*)d_ws;
    float* off = (float*)(ws + 0);               // 3,538,944 B
    float* xT  = (float*)(ws + 3538944);         // 8,388,608 B
    short* Ahi = (short*)(ws + 11927552);        // 73,728 B
    short* Alo = (short*)(ws + 12001280);        // 73,728 B
    short* Ohi = (short*)(ws + 12075008);        // 36,864 B
    short* Olo = (short*)(ws + 12111872);        // 36,864 B  (end 12,148,736)

    transpose_x_kernel<<<Bc * Hc * 2, 256, 0, stream>>>(x, xT);
    pack_weights_kernel<<<216, 256, 0, stream>>>(weight, offset_w, Ahi, Alo, Ohi, Olo);
    offsets_mfma_kernel<<<Bc * Hc * 2, 256, 0, stream>>>(xT, Ohi, Olo, offset_b, off);
    deform_main_kernel<<<Bc * Hc * 2, 256, 0, stream>>>(xT, Ahi, Alo, bias, off, out);
}

// Round 4
// 104.409 us; speedup vs baseline: 2.1188x; 1.3015x over previous
//
#include <hip/hip_runtime.h>
#include <hip/hip_bf16.h>

typedef __attribute__((ext_vector_type(8))) short bf16x8;
typedef __attribute__((ext_vector_type(4))) short bf16x4;
typedef __attribute__((ext_vector_type(4))) float f32x4;

#define Bc 2
#define Cc 64
#define Hc 128
#define Wc 128
#define Oc 64
#define NOFF 27
#define HWc (Hc * Wc)   // 16384

__device__ __forceinline__ short f2bf(float f) {
    __hip_bfloat16 h = __float2bfloat16(f);
    return __builtin_bit_cast(short, h);
}
__device__ __forceinline__ float bf2f(short s) {
    __hip_bfloat16 h = __builtin_bit_cast(__hip_bfloat16, s);
    return __bfloat162float(h);
}

// ---------------------------------------------------------------------------
// Kernel P: prep = transpose x (blocks 0..511) + pack weights (blocks 512..727)
// transpose: NCHW -> NHWC fp32, one (b,h,64px half-row) per block.
// pack: A-fragment layout, split bf16 hi/lo. A[m=o][k=kk*64+c].
//   lane L holds A[L&15][(L>>4)*8+j]; element ((mt*18+ksg)*64+lane)*8+j.
// ---------------------------------------------------------------------------
__global__ __launch_bounds__(256) void prep_kernel(
    const float* __restrict__ x, const float* __restrict__ w, const float* __restrict__ ow,
    float* __restrict__ xT, short* __restrict__ Ahi, short* __restrict__ Alo,
    short* __restrict__ Ohi, short* __restrict__ Olo) {
    int bid = blockIdx.x;
    int t = threadIdx.x;
    if (bid < 512) {
        int b = bid >> 8, rem = bid & 255;
        int h = rem >> 1, w0 = (rem & 1) << 6;
        __shared__ float tile[64][68];
        {
            int c = t >> 2, sub = t & 3;
            const float* src = x + ((size_t)(b * Cc + c) * Hc + h) * Wc + w0 + sub * 16;
#pragma unroll
            for (int j = 0; j < 4; ++j)
                *(float4*)&tile[c][sub * 16 + 4 * j] = *(const float4*)(src + 4 * j);
        }
        __syncthreads();
        {
            int ww = t >> 2, cs = (t & 3) << 4;
            float* dst = xT + (((size_t)(b * Hc + h)) * Wc + w0 + ww) * Cc + cs;
#pragma unroll
            for (int j = 0; j < 4; ++j) {
                float4 v = make_float4(tile[cs + 4 * j + 0][ww], tile[cs + 4 * j + 1][ww],
                                       tile[cs + 4 * j + 2][ww], tile[cs + 4 * j + 3][ww]);
                *(float4*)(dst + 4 * j) = v;
            }
        }
    } else {
        int idx = (bid - 512) * 256 + t;
        const int NM = 4 * 18 * 64 * 8;   // 36864
        const int NO = 2 * 18 * 64 * 8;   // 18432
        if (idx < NM) {
            int j = idx & 7, lane = (idx >> 3) & 63, ks = (idx >> 9) % 18, mt = idx / 9216;
            int o  = mt * 16 + (lane & 15);
            int kk = ks >> 1;
            int c  = (ks & 1) * 32 + (lane >> 4) * 8 + j;
            float v = w[(o * Cc + c) * 9 + kk];
            short hi = f2bf(v);
            short lo = f2bf(v - bf2f(hi));
            Ahi[idx] = hi; Alo[idx] = lo;
        } else if (idx < NM + NO) {
            int t2 = idx - NM;
            int j = t2 & 7, lane = (t2 >> 3) & 63, ks = (t2 >> 9) % 18, mt = t2 / 9216;
            int o  = mt * 16 + (lane & 15);
            int kk = ks >> 1;
            int c  = (ks & 1) * 32 + (lane >> 4) * 8 + j;
            float v = (o < NOFF) ? ow[(o * Cc + c) * 9 + kk] : 0.f;
            short hi = f2bf(v);
            short lo = f2bf(v - bf2f(hi));
            Ohi[t2] = hi; Olo[t2] = lo;
        }
    }
}

// ---------------------------------------------------------------------------
// Kernel F: fused offsets-GEMM -> bilinear table -> main deformable GEMM.
// block = 256 thr (4 waves), one (b,h,64px) tile. grid = B*H*2 = 512.
// Stage 1: offsets conv, M=32(27) N=64 K=576, result -> LDS tmp.
// Stage 2: main conv,    M=64     N=64 K=576, bilinear-sampled B.
// Both stages: prefetch next tap's gathers during MFMA phase (MLP);
// Bl B-tile swizzled (n ^= (quad&1)<<2) to break the 8-way write conflict.
// ---------------------------------------------------------------------------
__global__ __launch_bounds__(256, 2) void fused_dcn_kernel(
    const float* __restrict__ xT,
    const short* __restrict__ Ahi, const short* __restrict__ Alo,
    const short* __restrict__ Ohi, const short* __restrict__ Olo,
    const float* __restrict__ bias, const float* __restrict__ obias,
    float* __restrict__ out) {
    int bid = blockIdx.x;
    int b = bid >> 8, rem = bid & 255;
    int h = rem >> 1, w0 = (rem & 1) << 6;
    int tid = threadIdx.x;
    int lane = tid & 63, wv = tid >> 6;
    int sub = tid & 15, pgg = tid >> 4;

    __shared__ float4 wgt[576];
    __shared__ int4   sidx[576];
    __shared__ __align__(16) short Bl[4096];
    __shared__ float  tmp[NOFF * 64];

    const float* xb = xT + (size_t)b * HWc * Cc;
    int ksw = sub >> 3, qw = (sub >> 1) & 3, jw = (sub & 1) * 4;
    int swz = (qw & 1) << 2;
    int rl  = lane ^ (((lane >> 4) & 1) << 2);   // swizzled read lane

    // ===================== Stage 1: offsets GEMM =====================
    f32x4 oacc0 = {0.f, 0.f, 0.f, 0.f}, oacc1 = {0.f, 0.f, 0.f, 0.f};
    float4 pre1[4];
    {   // prefetch tap 0 (di=-1, dj=-1)
        int yc = min(max(h - 1, 0), Hc - 1);
#pragma unroll
        for (int i = 0; i < 4; ++i) {
            int xc = min(max(w0 + pgg + 16 * i - 1, 0), Wc - 1);
            pre1[i] = *(const float4*)(xb + ((size_t)yc * Wc + xc) * Cc + sub * 4);
        }
    }
    for (int kk = 0; kk < 9; ++kk) {
        int di = kk / 3 - 1, dj = kk % 3 - 1;
        int y = h + di;
        bool vy = (y >= 0) && (y < Hc);
        bf16x4 sv[4];
#pragma unroll
        for (int i = 0; i < 4; ++i) {
            int xw = w0 + pgg + 16 * i + dj;
            float m = (vy && xw >= 0 && xw < Wc) ? 1.f : 0.f;
            sv[i][0] = f2bf(pre1[i].x * m);
            sv[i][1] = f2bf(pre1[i].y * m);
            sv[i][2] = f2bf(pre1[i].z * m);
            sv[i][3] = f2bf(pre1[i].w * m);
        }
        __syncthreads();
#pragma unroll
        for (int i = 0; i < 4; ++i) {
            int slot = (i * 2 + ksw) * 64 + qw * 16 + (pgg ^ swz);
            *(bf16x4*)(&Bl[slot * 8 + jw]) = sv[i];
        }
        __syncthreads();
        if (kk < 8) {   // prefetch next tap during MFMA
            int kk2 = kk + 1;
            int yc = min(max(h + kk2 / 3 - 1, 0), Hc - 1);
            int dj2 = kk2 % 3 - 1;
#pragma unroll
            for (int i = 0; i < 4; ++i) {
                int xc = min(max(w0 + pgg + 16 * i + dj2, 0), Wc - 1);
                pre1[i] = *(const float4*)(xb + ((size_t)yc * Wc + xc) * Cc + sub * 4);
            }
        }
#pragma unroll
        for (int ks = 0; ks < 2; ++ks) {
            bf16x8 bf = *(const bf16x8*)(&Bl[((wv * 2 + ks) * 64 + rl) * 8]);
            int ksg = kk * 2 + ks;
            bf16x8 ah0 = *(const bf16x8*)(Ohi + ((0 * 18 + ksg) * 64 + lane) * 8);
            bf16x8 al0 = *(const bf16x8*)(Olo + ((0 * 18 + ksg) * 64 + lane) * 8);
            oacc0 = __builtin_amdgcn_mfma_f32_16x16x32_bf16(ah0, bf, oacc0, 0, 0, 0);
            oacc0 = __builtin_amdgcn_mfma_f32_16x16x32_bf16(al0, bf, oacc0, 0, 0, 0);
            bf16x8 ah1 = *(const bf16x8*)(Ohi + ((1 * 18 + ksg) * 64 + lane) * 8);
            bf16x8 al1 = *(const bf16x8*)(Olo + ((1 * 18 + ksg) * 64 + lane) * 8);
            oacc1 = __builtin_amdgcn_mfma_f32_16x16x32_bf16(ah1, bf, oacc1, 0, 0, 0);
            oacc1 = __builtin_amdgcn_mfma_f32_16x16x32_bf16(al1, bf, oacc1, 0, 0, 0);
        }
    }
    {   // offsets tile -> LDS tmp[ch][p]
        int pl = wv * 16 + (lane & 15);
        int mrow = (lane >> 4) * 4;
#pragma unroll
        for (int r = 0; r < 4; ++r) {
            int oc = mrow + r;
            if (oc < NOFF) tmp[oc * 64 + pl] = oacc0[r] + obias[oc];
            int oc2 = 16 + mrow + r;
            if (oc2 < NOFF) tmp[oc2 * 64 + pl] = oacc1[r] + obias[oc2];
        }
    }
    __syncthreads();

    // ===================== bilinear table =====================
    for (int t = tid; t < 576; t += 256) {
        int k = t >> 6, p = t & 63;
        float dy = tmp[k * 64 + p];
        float dx = tmp[(9 + k) * 64 + p];
        float mm = tmp[(18 + k) * 64 + p];
        float m  = 1.f / (1.f + __expf(-mm));
        float py = (float)(h - 1 + k / 3) + dy;
        float px = (float)(w0 + p - 1 + k % 3) + dx;
        float y0f = floorf(py), x0f = floorf(px);
        float fy = py - y0f, fx = px - x0f;
        int y0 = (int)y0f, x0i = (int)x0f;
        float vy0 = (y0 >= 0 && y0 < Hc) ? 1.f : 0.f;
        float vy1 = (y0 + 1 >= 0 && y0 + 1 < Hc) ? 1.f : 0.f;
        float vx0 = (x0i >= 0 && x0i < Wc) ? 1.f : 0.f;
        float vx1 = (x0i + 1 >= 0 && x0i + 1 < Wc) ? 1.f : 0.f;
        wgt[t] = make_float4((1.f - fy) * (1.f - fx) * m * vy0 * vx0,
                             (1.f - fy) * fx         * m * vy0 * vx1,
                             fy         * (1.f - fx) * m * vy1 * vx0,
                             fy         * fx         * m * vy1 * vx1);
        int cy0 = min(max(y0, 0), Hc - 1) * Wc;
        int cy1 = min(max(y0 + 1, 0), Hc - 1) * Wc;
        int cx0 = min(max(x0i, 0), Wc - 1);
        int cx1 = min(max(x0i + 1, 0), Wc - 1);
        sidx[t] = make_int4(cy0 + cx0, cy0 + cx1, cy1 + cx0, cy1 + cx1);
    }
    __syncthreads();

    // ===================== Stage 2: main GEMM =====================
    f32x4 acc[4] = {{0.f, 0.f, 0.f, 0.f}, {0.f, 0.f, 0.f, 0.f},
                    {0.f, 0.f, 0.f, 0.f}, {0.f, 0.f, 0.f, 0.f}};
    float4 pre[16];
    const float* bp = xb + sub * 4;
#pragma unroll
    for (int i = 0; i < 4; ++i) {   // prefetch tap 0
        int4 id = sidx[pgg + 16 * i];
        pre[i * 4 + 0] = *(const float4*)(bp + (size_t)id.x * Cc);
        pre[i * 4 + 1] = *(const float4*)(bp + (size_t)id.y * Cc);
        pre[i * 4 + 2] = *(const float4*)(bp + (size_t)id.z * Cc);
        pre[i * 4 + 3] = *(const float4*)(bp + (size_t)id.w * Cc);
    }
    for (int kk = 0; kk < 9; ++kk) {
        bf16x4 sv[4];
#pragma unroll
        for (int i = 0; i < 4; ++i) {
            float4 w4 = wgt[kk * 64 + pgg + 16 * i];
            float4 v00 = pre[i * 4 + 0], v01 = pre[i * 4 + 1];
            float4 v10 = pre[i * 4 + 2], v11 = pre[i * 4 + 3];
            sv[i][0] = f2bf(w4.x * v00.x + w4.y * v01.x + w4.z * v10.x + w4.w * v11.x);
            sv[i][1] = f2bf(w4.x * v00.y + w4.y * v01.y + w4.z * v10.y + w4.w * v11.y);
            sv[i][2] = f2bf(w4.x * v00.z + w4.y * v01.z + w4.z * v10.z + w4.w * v11.z);
            sv[i][3] = f2bf(w4.x * v00.w + w4.y * v01.w + w4.z * v10.w + w4.w * v11.w);
        }
        __syncthreads();
#pragma unroll
        for (int i = 0; i < 4; ++i) {
            int slot = (i * 2 + ksw) * 64 + qw * 16 + (pgg ^ swz);
            *(bf16x4*)(&Bl[slot * 8 + jw]) = sv[i];
        }
        __syncthreads();
        if (kk < 8) {   // prefetch next tap during MFMA
#pragma unroll
            for (int i = 0; i < 4; ++i) {
                int4 id = sidx[(kk + 1) * 64 + pgg + 16 * i];
                pre[i * 4 + 0] = *(const float4*)(bp + (size_t)id.x * Cc);
                pre[i * 4 + 1] = *(const float4*)(bp + (size_t)id.y * Cc);
                pre[i * 4 + 2] = *(const float4*)(bp + (size_t)id.z * Cc);
                pre[i * 4 + 3] = *(const float4*)(bp + (size_t)id.w * Cc);
            }
        }
#pragma unroll
        for (int ks = 0; ks < 2; ++ks) {
            bf16x8 bf = *(const bf16x8*)(&Bl[((wv * 2 + ks) * 64 + rl) * 8]);
            int ksg = kk * 2 + ks;
#pragma unroll
            for (int mt = 0; mt < 4; ++mt) {
                bf16x8 ah = *(const bf16x8*)(Ahi + ((mt * 18 + ksg) * 64 + lane) * 8);
                bf16x8 al = *(const bf16x8*)(Alo + ((mt * 18 + ksg) * 64 + lane) * 8);
                acc[mt] = __builtin_amdgcn_mfma_f32_16x16x32_bf16(ah, bf, acc[mt], 0, 0, 0);
                acc[mt] = __builtin_amdgcn_mfma_f32_16x16x32_bf16(al, bf, acc[mt], 0, 0, 0);
            }
        }
    }

    // ===================== epilogue =====================
    int pl = wv * 16 + (lane & 15);
    int mrow = (lane >> 4) * 4;
    float* ob = out + ((size_t)b * Oc * Hc + h) * Wc + w0 + pl;
#pragma unroll
    for (int mt = 0; mt < 4; ++mt)
#pragma unroll
        for (int r = 0; r < 4; ++r) {
            int o = mt * 16 + mrow + r;
            ob[(size_t)o * HWc] = acc[mt][r] + bias[o];
        }
}

// ---------------------------------------------------------------------------
extern "C" void kernel_launch(void* const* d_in, const int* in_sizes, int n_in,
                              void* d_out, int out_size, void* d_ws, size_t ws_size,
                              hipStream_t stream) {
    const float* x        = (const float*)d_in[0];
    const float* weight   = (const float*)d_in[1];
    const float* bias     = (const float*)d_in[2];
    const float* offset_w = (const float*)d_in[3];
    const float* offset_b = (const float*)d_in[4];
    float* out = (float*)d_out;

    char* ws = (char*)d_ws;
    float* xT  = (float*)(ws + 0);              // 8,388,608 B
    short* Ahi = (short*)(ws + 8388608);        // 73,728 B
    short* Alo = (short*)(ws + 8462336);        // 73,728 B
    short* Ohi = (short*)(ws + 8536064);        // 36,864 B
    short* Olo = (short*)(ws + 8572928);        // 36,864 B  (end 8,609,792)

    prep_kernel<<<512 + 216, 256, 0, stream>>>(x, weight, offset_w, xT, Ahi, Alo, Ohi, Olo);
    fused_dcn_kernel<<<Bc * Hc * 2, 256, 0, stream>>>(xT, Ahi, Alo, Ohi, Olo, bias, offset_b, out);
}